// Round 13
// baseline (400.528 us; speedup 1.0000x reference)
//
#include <hip/hip_runtime.h>

#define N_NODES 100000
#define E_EDGES 1600000
#define F_DIM 128
#define ALPHA 0.2f

#define BSH 8
#define NBUCK ((N_NODES + 255) >> 8)      // 391
#define NHB 400                            // hist/scatter blocks
#define EPB 4000                           // 400*4000 = 1.6M exactly
#define SCAN_TOTAL (NBUCK * NHB)           // 156400
#define SEG ((SCAN_TOTAL + 1023) / 1024)   // 153
#define SCORE_BLOCKS (N_NODES / 16)        // 6250

__device__ __forceinline__ float bf2f(unsigned short s) {
    return __uint_as_float((unsigned)s << 16);
}
__device__ __forceinline__ unsigned short f2bf(float f) {
    unsigned u = __float_as_uint(f);
    return (unsigned short)((u + 0x7FFFu + ((u >> 16) & 1u)) >> 16);  // RNE
}

// ===========================================================================
// K1: fused score + pass-1 coarse histogram (src>>8 into cm[bucket][blk]).
// Hist: LDS-only; each (bucket,blk) cell exclusive -> plain store, no memset.
// ===========================================================================
__global__ void fused_score_hist_kernel(const float* __restrict__ h,
                                        const float* __restrict__ a,
                                        float* __restrict__ s_left,
                                        float* __restrict__ s_right,
                                        unsigned short* __restrict__ h_bf16,
                                        const int* __restrict__ src,
                                        int* __restrict__ cm) {
    const int b = blockIdx.x;
    if (b < NHB) {
        __shared__ int lh[NBUCK];
        for (int k = threadIdx.x; k < NBUCK; k += 256) lh[k] = 0;
        __syncthreads();
        const int e0 = b * EPB;
        for (int i = threadIdx.x; i < EPB; i += 256) {
            const int s = __builtin_nontemporal_load(&src[e0 + i]);
            atomicAdd(&lh[s >> BSH], 1);
        }
        __syncthreads();
        for (int k = threadIdx.x; k < NBUCK; k += 256)
            cm[k * NHB + b] = lh[k];
    } else {
        // ---- score role: 16 nodes per block, 16 lanes per node ----
        const int sb   = b - NHB;
        const int lane = threadIdx.x & 63;
        const int sub  = lane & 15;
        const int node = sb * 16 + (threadIdx.x >> 6) * 4 + (lane >> 4);

        const float4* __restrict__ h4 = reinterpret_cast<const float4*>(h);
        const float4* __restrict__ a4 = reinterpret_cast<const float4*>(a);

        const float4 ha = h4[(size_t)node * 32 + sub * 2];
        const float4 hb = h4[(size_t)node * 32 + sub * 2 + 1];
        const float4 al0 = a4[sub * 2],      al1 = a4[sub * 2 + 1];
        const float4 ar0 = a4[32 + sub * 2], ar1 = a4[32 + sub * 2 + 1];

        ushort4 o0, o1;
        o0.x = f2bf(ha.x); o0.y = f2bf(ha.y); o0.z = f2bf(ha.z); o0.w = f2bf(ha.w);
        o1.x = f2bf(hb.x); o1.y = f2bf(hb.y); o1.z = f2bf(hb.z); o1.w = f2bf(hb.w);
        ushort4* hbw = reinterpret_cast<ushort4*>(h_bf16);
        hbw[(size_t)node * 32 + sub * 2]     = o0;
        hbw[(size_t)node * 32 + sub * 2 + 1] = o1;

        float pl = ha.x * al0.x + ha.y * al0.y + ha.z * al0.z + ha.w * al0.w
                 + hb.x * al1.x + hb.y * al1.y + hb.z * al1.z + hb.w * al1.w;
        float pr = ha.x * ar0.x + ha.y * ar0.y + ha.z * ar0.z + ha.w * ar0.w
                 + hb.x * ar1.x + hb.y * ar1.y + hb.z * ar1.z + hb.w * ar1.w;

        #pragma unroll
        for (int off = 8; off > 0; off >>= 1) {
            pl += __shfl_down(pl, off);
            pr += __shfl_down(pr, off);
        }
        if (sub == 0) {
            s_left[node]  = pl;
            s_right[node] = pr;
        }
    }
}

// ===========================================================================
// K2: in-place exclusive scan of cm (156400 cells, bucket-major), one block
// of 1024 threads, 153 cells/thread (bounds-checked). Emits bucketbase and
// the row_start sentinel.
// ===========================================================================
__global__ void chunk_scan_kernel(int* __restrict__ cm,
                                  int* __restrict__ bucketbase,
                                  int* __restrict__ row_start) {
    __shared__ int s[1024];
    const int t = threadIdx.x;
    const int beg = t * SEG;
    const int end = min(beg + SEG, SCAN_TOTAL);
    int sum = 0;
    for (int i = beg; i < end; ++i) sum += cm[i];
    s[t] = sum;
    __syncthreads();
    for (int off = 1; off < 1024; off <<= 1) {
        const int v = (t >= off) ? s[t - off] : 0;
        __syncthreads();
        s[t] += v;
        __syncthreads();
    }
    int base = s[t] - sum;                        // exclusive over threads
    for (int i = beg; i < end; ++i) {
        const int v = cm[i];
        cm[i] = base;
        base += v;
    }
    __syncthreads();                              // block-global writes visible
    if (t < NBUCK) bucketbase[t] = cm[t * NHB];
    if (t == 0) {
        bucketbase[NBUCK] = E_EDGES;
        row_start[N_NODES] = E_EDGES;
    }
}

// ===========================================================================
// K3: re-stream edges; LDS cursors from cm -> (src&255)<<17|dst records into
// bucket-contiguous chunks. Each block's chunk lines are L2-resident and fill
// densely -> full write combining (no random-line thrash).
// ===========================================================================
__global__ void bucket_scatter_kernel(const int* __restrict__ src,
                                      const int* __restrict__ dst,
                                      const int* __restrict__ cm,
                                      unsigned int* __restrict__ bucket_arr) {
    __shared__ int cur[NBUCK];
    const int b = blockIdx.x;
    for (int k = threadIdx.x; k < NBUCK; k += 256) cur[k] = cm[k * NHB + b];
    __syncthreads();
    const int e0 = b * EPB;
    for (int i = threadIdx.x; i < EPB; i += 256) {
        const int s = __builtin_nontemporal_load(&src[e0 + i]);
        const unsigned int d = (unsigned int)__builtin_nontemporal_load(&dst[e0 + i]);
        const int r = atomicAdd(&cur[s >> BSH], 1);          // LDS atomic
        bucket_arr[r] = ((unsigned int)(s & 255) << 17) | d;
    }
}

// ===========================================================================
// K4: one block per bucket (~4096 edges, 16KB, L2-hot). LDS count of 256
// srcs -> wave-0 scan -> exact row_start + grouped dst-only pairs.
// ===========================================================================
__global__ void bucket_sort_kernel(const unsigned int* __restrict__ bucket_arr,
                                   const int* __restrict__ bucketbase,
                                   int* __restrict__ row_start,
                                   unsigned int* __restrict__ pairs) {
    __shared__ int c[256];
    __shared__ int cur[256];
    const int b = blockIdx.x;
    const int tid = threadIdx.x;
    const int base = bucketbase[b];
    const int end  = bucketbase[b + 1];
    const int srcbase = b << BSH;
    const int nsrc = min(256, N_NODES - srcbase);

    c[tid] = 0;
    __syncthreads();
    for (int i = base + tid; i < end; i += 256)
        atomicAdd(&c[bucket_arr[i] >> 17], 1);
    __syncthreads();

    if (tid < 64) {                               // wave 0: exclusive scan of 256
        int loc[4]; int lsum = 0;
        #pragma unroll
        for (int q = 0; q < 4; ++q) { loc[q] = c[tid * 4 + q]; lsum += loc[q]; }
        int inc = lsum;
        #pragma unroll
        for (int off = 1; off < 64; off <<= 1) {
            const int v = __shfl_up(inc, off);
            if (tid >= off) inc += v;
        }
        int eb = inc - lsum;                      // exclusive over lanes
        #pragma unroll
        for (int q = 0; q < 4; ++q) {
            const int v = loc[q];
            c[tid * 4 + q]   = eb;
            cur[tid * 4 + q] = eb;
            eb += v;
        }
    }
    __syncthreads();

    if (tid < nsrc) row_start[srcbase + tid] = base + c[tid];

    for (int i = base + tid; i < end; i += 256) {
        const unsigned int rec = bucket_arr[i];   // L2-hot re-read
        const int ls = (int)(rec >> 17);
        const int pos = base + atomicAdd(&cur[ls], 1);
        pairs[pos] = rec & 0x1FFFFu;
    }
}

// ===========================================================================
// K5: gather (r10/r12-proven CSR bf16 gather; ee computed in preload).
// ===========================================================================
__global__ void gather_bf16_kernel(const unsigned short* __restrict__ h_bf16,
                                   const float* __restrict__ s_left,
                                   const float* __restrict__ s_right,
                                   const int* __restrict__ row_start,
                                   const unsigned int* __restrict__ pairs,
                                   float* __restrict__ out) {
    const int gtid = blockIdx.x * blockDim.x + threadIdx.x;
    const int node = gtid >> 6;
    const int lane = threadIdx.x & 63;
    if (node >= N_NODES) return;

    const int beg = row_start[node];
    const int end = row_start[node + 1];
    const float sl = s_left[node];

    const int half = lane >> 5;
    const int hl   = lane & 31;
    const ushort4* __restrict__ hb4 = reinterpret_cast<const ushort4*>(h_bf16);

    float4 acc = make_float4(0.0f, 0.0f, 0.0f, 0.0f);
    float rs = 0.0f;

    for (int base = beg; base < end; base += 64) {
        const int m = min(64, end - base);   // wave-uniform
        int pd = 0; float pe = 0.0f;
        if (lane < m) {
            const unsigned int rec = __builtin_nontemporal_load(&pairs[base + lane]);
            pd = (int)rec;
            const float score = sl + s_right[pd];
            const float lr = score > 0.0f ? score : ALPHA * score;
            pe = __expf(-lr);
        }

        int j = 0;  // uniform across all lanes from here (r3 lesson)
        for (; j + 16 <= m; j += 16) {
            const int jj = j + half;
            int   d[8]; float e[8];
            #pragma unroll
            for (int k = 0; k < 8; ++k) {
                d[k] = __shfl(pd, jj + 2 * k);
                e[k] = __shfl(pe, jj + 2 * k);
            }
            ushort4 u[8];
            #pragma unroll
            for (int k = 0; k < 8; ++k) u[k] = hb4[(size_t)d[k] * 32 + hl];
            #pragma unroll
            for (int k = 0; k < 8; ++k) {
                rs    += e[k];
                acc.x += e[k] * bf2f(u[k].x);
                acc.y += e[k] * bf2f(u[k].y);
                acc.z += e[k] * bf2f(u[k].z);
                acc.w += e[k] * bf2f(u[k].w);
            }
        }
        for (; j + 8 <= m; j += 8) {
            const int jj = j + half;
            int   d[4]; float e[4];
            #pragma unroll
            for (int k = 0; k < 4; ++k) {
                d[k] = __shfl(pd, jj + 2 * k);
                e[k] = __shfl(pe, jj + 2 * k);
            }
            ushort4 u[4];
            #pragma unroll
            for (int k = 0; k < 4; ++k) u[k] = hb4[(size_t)d[k] * 32 + hl];
            #pragma unroll
            for (int k = 0; k < 4; ++k) {
                rs    += e[k];
                acc.x += e[k] * bf2f(u[k].x);
                acc.y += e[k] * bf2f(u[k].y);
                acc.z += e[k] * bf2f(u[k].z);
                acc.w += e[k] * bf2f(u[k].w);
            }
        }
        for (; j + 2 <= m; j += 2) {
            const int jj = j + half;
            const int   dd = __shfl(pd, jj);
            const float ee = __shfl(pe, jj);
            const ushort4 u = hb4[(size_t)dd * 32 + hl];
            rs += ee;
            acc.x += ee * bf2f(u.x);
            acc.y += ee * bf2f(u.y);
            acc.z += ee * bf2f(u.z);
            acc.w += ee * bf2f(u.w);
        }
        if (j < m) {
            const int   dd = __shfl(pd, j);
            float       ee = __shfl(pe, j);
            if (half == 1) ee = 0.0f;
            const ushort4 u = hb4[(size_t)dd * 32 + hl];
            rs += ee;
            acc.x += ee * bf2f(u.x);
            acc.y += ee * bf2f(u.y);
            acc.z += ee * bf2f(u.z);
            acc.w += ee * bf2f(u.w);
        }
    }

    acc.x += __shfl_xor(acc.x, 32);
    acc.y += __shfl_xor(acc.y, 32);
    acc.z += __shfl_xor(acc.z, 32);
    acc.w += __shfl_xor(acc.w, 32);
    rs    += __shfl_xor(rs, 32);

    if (half == 0) {
        const float inv = 1.0f / rs;
        float4 o;
        o.x = fmaxf(acc.x * inv, 0.0f);
        o.y = fmaxf(acc.y * inv, 0.0f);
        o.z = fmaxf(acc.z * inv, 0.0f);
        o.w = fmaxf(acc.w * inv, 0.0f);
        reinterpret_cast<float4*>(out)[(size_t)node * 32 + hl] = o;
    }
}

// ===========================================================================
// Last-resort fallback (atomic path, 1.2 MB).
// ===========================================================================
__global__ void score_kernel(const float* __restrict__ h,
                             const float* __restrict__ a,
                             float* __restrict__ s_left,
                             float* __restrict__ s_right) {
    const int gtid = blockIdx.x * blockDim.x + threadIdx.x;
    const int node = gtid >> 6;
    const int lane = threadIdx.x & 63;
    if (node >= N_NODES) return;
    const float2 hv = reinterpret_cast<const float2*>(h + (size_t)node * F_DIM)[lane];
    const float2 al = reinterpret_cast<const float2*>(a)[lane];
    const float2 ar = reinterpret_cast<const float2*>(a + F_DIM)[lane];
    float pl = hv.x * al.x + hv.y * al.y;
    float pr = hv.x * ar.x + hv.y * ar.y;
    #pragma unroll
    for (int off = 32; off > 0; off >>= 1) {
        pl += __shfl_down(pl, off);
        pr += __shfl_down(pr, off);
    }
    if (lane == 0) { s_left[node] = pl; s_right[node] = pr; }
}

__global__ void edge_atomic_kernel(const float* __restrict__ h,
                                   const int* __restrict__ src,
                                   const int* __restrict__ dst,
                                   const float* __restrict__ s_left,
                                   const float* __restrict__ s_right,
                                   float* __restrict__ out,
                                   float* __restrict__ rowsum) {
    const int gtid = blockIdx.x * blockDim.x + threadIdx.x;
    const int e = gtid >> 6;
    const int lane = threadIdx.x & 63;
    if (e >= E_EDGES) return;
    const int s = src[e];
    const int d = dst[e];
    const float score = s_left[s] + s_right[d];
    const float lr = score > 0.0f ? score : ALPHA * score;
    const float ee = __expf(-lr);
    if (lane == 0) atomicAdd(&rowsum[s], ee);
    const float2 hv = reinterpret_cast<const float2*>(h + (size_t)d * F_DIM)[lane];
    float* o = out + (size_t)s * F_DIM + (size_t)lane * 2;
    atomicAdd(o,     ee * hv.x);
    atomicAdd(o + 1, ee * hv.y);
}

__global__ void finalize_kernel(float* __restrict__ out,
                                const float* __restrict__ rowsum) {
    const int i = blockIdx.x * blockDim.x + threadIdx.x;
    const int total = N_NODES * (F_DIM / 4);
    if (i >= total) return;
    const int n = i / (F_DIM / 4);
    const float inv = 1.0f / rowsum[n];
    float4 v = reinterpret_cast<float4*>(out)[i];
    v.x = fmaxf(v.x * inv, 0.0f);
    v.y = fmaxf(v.y * inv, 0.0f);
    v.z = fmaxf(v.z * inv, 0.0f);
    v.w = fmaxf(v.w * inv, 0.0f);
    reinterpret_cast<float4*>(out)[i] = v;
}

extern "C" void kernel_launch(void* const* d_in, const int* in_sizes, int n_in,
                              void* d_out, int out_size, void* d_ws, size_t ws_size,
                              hipStream_t stream) {
    const float* h    = (const float*)d_in[0];   // [N, F]
    const float* a    = (const float*)d_in[1];   // [1, 2F]
    const int*   edge = (const int*)d_in[2];     // [2, E]
    const int*   src  = edge;
    const int*   dst  = edge + E_EDGES;
    float* out = (float*)d_out;

    const int wpb = 256 / 64;

    // ---- SORT TIER (~40.3 MB; ws >= 52.5 MB proven in r11) ----
    {
        char* wp = (char*)d_ws;
        unsigned int* pairs      = (unsigned int*)wp;  wp += (size_t)E_EDGES * sizeof(unsigned int); // 6.4MB
        unsigned int* bucket_arr = (unsigned int*)wp;  wp += (size_t)E_EDGES * sizeof(unsigned int); // 6.4MB
        float* s_left    = (float*)wp;   wp += (size_t)N_NODES * sizeof(float);
        float* s_right   = (float*)wp;   wp += (size_t)N_NODES * sizeof(float);
        int*   row_start = (int*)wp;     wp += (size_t)(N_NODES + 1) * sizeof(int);
        int*   cm        = (int*)wp;     wp += (size_t)SCAN_TOTAL * sizeof(int);    // 625.6KB
        int*   bucketbase= (int*)wp;     wp += (size_t)(NBUCK + 1) * sizeof(int);
        unsigned short* h_bf16 = (unsigned short*)wp;
        wp += (size_t)N_NODES * F_DIM * sizeof(unsigned short);                      // 25.6MB
        const size_t needed = (size_t)(wp - (char*)d_ws);

        if (ws_size >= needed) {
            fused_score_hist_kernel<<<NHB + SCORE_BLOCKS, 256, 0, stream>>>(
                h, a, s_left, s_right, h_bf16, src, cm);
            chunk_scan_kernel<<<1, 1024, 0, stream>>>(cm, bucketbase, row_start);
            bucket_scatter_kernel<<<NHB, 256, 0, stream>>>(src, dst, cm, bucket_arr);
            bucket_sort_kernel<<<NBUCK, 256, 0, stream>>>(
                bucket_arr, bucketbase, row_start, pairs);
            gather_bf16_kernel<<<(N_NODES + wpb - 1) / wpb, 256, 0, stream>>>(
                h_bf16, s_left, s_right, row_start, pairs, out);
            return;
        }
    }

    // ---- FALLBACK: atomic path (1.2 MB) ----
    float* fsl = (float*)d_ws;
    float* fsr = fsl + N_NODES;
    float* frs = fsr + N_NODES;
    (void)hipMemsetAsync(d_out, 0, (size_t)N_NODES * F_DIM * sizeof(float), stream);
    (void)hipMemsetAsync(frs, 0, (size_t)N_NODES * sizeof(float), stream);
    score_kernel<<<(N_NODES + wpb - 1) / wpb, 256, 0, stream>>>(h, a, fsl, fsr);
    edge_atomic_kernel<<<(E_EDGES + wpb - 1) / wpb, 256, 0, stream>>>(
        h, src, dst, fsl, fsr, out, frs);
    const int total = N_NODES * (F_DIM / 4);
    finalize_kernel<<<(total + 255) / 256, 256, 0, stream>>>(out, frs);
}

// Round 14
// 133.010 us; speedup vs baseline: 3.0113x; 3.0113x over previous
//
#include <hip/hip_runtime.h>

#define N_NODES 100000
#define E_EDGES 1600000
#define F_DIM 128
#define ALPHA 0.2f

#define BSH 8
#define NBUCK ((N_NODES + 255) >> 8)      // 391
#define NHB 400                            // hist/scatter blocks
#define EPB 4000                           // 400*4000 = 1.6M exactly
#define SCORE_BLOCKS (N_NODES / 16)        // 6250

__device__ __forceinline__ float bf2f(unsigned short s) {
    return __uint_as_float((unsigned)s << 16);
}
__device__ __forceinline__ unsigned short f2bf(float f) {
    unsigned u = __float_as_uint(f);
    return (unsigned short)((u + 0x7FFFu + ((u >> 16) & 1u)) >> 16);  // RNE
}

// ===========================================================================
// K1: fused score + pass-1 coarse histogram (src>>8 into cm[bucket][blk]).
// Hist: LDS-only; each (bucket,blk) cell exclusive -> plain store, no memset.
// ===========================================================================
__global__ void fused_score_hist_kernel(const float* __restrict__ h,
                                        const float* __restrict__ a,
                                        float* __restrict__ s_left,
                                        float* __restrict__ s_right,
                                        unsigned short* __restrict__ h_bf16,
                                        const int* __restrict__ src,
                                        int* __restrict__ cm) {
    const int b = blockIdx.x;
    if (b < NHB) {
        __shared__ int lh[NBUCK];
        for (int k = threadIdx.x; k < NBUCK; k += 256) lh[k] = 0;
        __syncthreads();
        const int e0 = b * EPB;
        for (int i = threadIdx.x; i < EPB; i += 256) {
            const int s = __builtin_nontemporal_load(&src[e0 + i]);
            atomicAdd(&lh[s >> BSH], 1);
        }
        __syncthreads();
        for (int k = threadIdx.x; k < NBUCK; k += 256)
            cm[k * NHB + b] = lh[k];
    } else {
        // ---- score role: 16 nodes per block, 16 lanes per node ----
        const int sb   = b - NHB;
        const int lane = threadIdx.x & 63;
        const int sub  = lane & 15;
        const int node = sb * 16 + (threadIdx.x >> 6) * 4 + (lane >> 4);

        const float4* __restrict__ h4 = reinterpret_cast<const float4*>(h);
        const float4* __restrict__ a4 = reinterpret_cast<const float4*>(a);

        const float4 ha = h4[(size_t)node * 32 + sub * 2];
        const float4 hb = h4[(size_t)node * 32 + sub * 2 + 1];
        const float4 al0 = a4[sub * 2],      al1 = a4[sub * 2 + 1];
        const float4 ar0 = a4[32 + sub * 2], ar1 = a4[32 + sub * 2 + 1];

        ushort4 o0, o1;
        o0.x = f2bf(ha.x); o0.y = f2bf(ha.y); o0.z = f2bf(ha.z); o0.w = f2bf(ha.w);
        o1.x = f2bf(hb.x); o1.y = f2bf(hb.y); o1.z = f2bf(hb.z); o1.w = f2bf(hb.w);
        ushort4* hbw = reinterpret_cast<ushort4*>(h_bf16);
        hbw[(size_t)node * 32 + sub * 2]     = o0;
        hbw[(size_t)node * 32 + sub * 2 + 1] = o1;

        float pl = ha.x * al0.x + ha.y * al0.y + ha.z * al0.z + ha.w * al0.w
                 + hb.x * al1.x + hb.y * al1.y + hb.z * al1.z + hb.w * al1.w;
        float pr = ha.x * ar0.x + ha.y * ar0.y + ha.z * ar0.z + ha.w * ar0.w
                 + hb.x * ar1.x + hb.y * ar1.y + hb.z * ar1.z + hb.w * ar1.w;

        #pragma unroll
        for (int off = 8; off > 0; off >>= 1) {
            pl += __shfl_down(pl, off);
            pr += __shfl_down(pr, off);
        }
        if (sub == 0) {
            s_left[node]  = pl;
            s_right[node] = pr;
        }
    }
}

// ===========================================================================
// K2a: per-bucket row scan. One block per bucket (391 blocks, 512 thr):
// LDS-scan the bucket's 400-cell row of cm in place (within-bucket exclusive
// prefix over hist blocks), emit the bucket total. Coalesced, parallel.
// ===========================================================================
__global__ void row_scan_kernel(int* __restrict__ cm,
                                int* __restrict__ btot) {
    __shared__ int s[512];
    const int k = blockIdx.x;
    const int t = threadIdx.x;
    const int v = (t < NHB) ? cm[k * NHB + t] : 0;
    s[t] = v;
    __syncthreads();
    #pragma unroll
    for (int off = 1; off < 512; off <<= 1) {
        const int u = (t >= off) ? s[t - off] : 0;
        __syncthreads();
        s[t] += u;
        __syncthreads();
    }
    if (t < NHB) cm[k * NHB + t] = s[t] - v;     // exclusive within row
    if (t == 511) btot[k] = s[511];              // row total
}

// ===========================================================================
// K2b: exclusive scan of the 391 bucket totals -> bucketbase + sentinels.
// ===========================================================================
__global__ void bucket_base_kernel(const int* __restrict__ btot,
                                   int* __restrict__ bucketbase,
                                   int* __restrict__ row_start) {
    __shared__ int s[512];
    const int t = threadIdx.x;
    const int v = (t < NBUCK) ? btot[t] : 0;
    s[t] = v;
    __syncthreads();
    #pragma unroll
    for (int off = 1; off < 512; off <<= 1) {
        const int u = (t >= off) ? s[t - off] : 0;
        __syncthreads();
        s[t] += u;
        __syncthreads();
    }
    if (t < NBUCK) bucketbase[t] = s[t] - v;
    if (t == 0) {
        bucketbase[NBUCK] = E_EDGES;
        row_start[N_NODES] = E_EDGES;
    }
}

// ===========================================================================
// K3: re-stream edges; LDS cursors = bucketbase[k] + cm[k][b] -> write
// (src&255)<<17|dst records into bucket-contiguous chunks (dense writes,
// full line combining).
// ===========================================================================
__global__ void bucket_scatter_kernel(const int* __restrict__ src,
                                      const int* __restrict__ dst,
                                      const int* __restrict__ cm,
                                      const int* __restrict__ bucketbase,
                                      unsigned int* __restrict__ bucket_arr) {
    __shared__ int cur[NBUCK];
    const int b = blockIdx.x;
    for (int k = threadIdx.x; k < NBUCK; k += 256)
        cur[k] = bucketbase[k] + cm[k * NHB + b];
    __syncthreads();
    const int e0 = b * EPB;
    for (int i = threadIdx.x; i < EPB; i += 256) {
        const int s = __builtin_nontemporal_load(&src[e0 + i]);
        const unsigned int d = (unsigned int)__builtin_nontemporal_load(&dst[e0 + i]);
        const int r = atomicAdd(&cur[s >> BSH], 1);          // LDS atomic
        bucket_arr[r] = ((unsigned int)(s & 255) << 17) | d;
    }
}

// ===========================================================================
// K4: one block per bucket (~4096 edges, 16KB, L2-hot). LDS count of 256
// srcs -> wave-0 scan -> exact row_start + grouped dst-only pairs.
// ===========================================================================
__global__ void bucket_sort_kernel(const unsigned int* __restrict__ bucket_arr,
                                   const int* __restrict__ bucketbase,
                                   int* __restrict__ row_start,
                                   unsigned int* __restrict__ pairs) {
    __shared__ int c[256];
    __shared__ int cur[256];
    const int b = blockIdx.x;
    const int tid = threadIdx.x;
    const int base = bucketbase[b];
    const int end  = bucketbase[b + 1];
    const int srcbase = b << BSH;
    const int nsrc = min(256, N_NODES - srcbase);

    c[tid] = 0;
    __syncthreads();
    for (int i = base + tid; i < end; i += 256)
        atomicAdd(&c[bucket_arr[i] >> 17], 1);
    __syncthreads();

    if (tid < 64) {                               // wave 0: exclusive scan of 256
        int loc[4]; int lsum = 0;
        #pragma unroll
        for (int q = 0; q < 4; ++q) { loc[q] = c[tid * 4 + q]; lsum += loc[q]; }
        int inc = lsum;
        #pragma unroll
        for (int off = 1; off < 64; off <<= 1) {
            const int v = __shfl_up(inc, off);
            if (tid >= off) inc += v;
        }
        int eb = inc - lsum;                      // exclusive over lanes
        #pragma unroll
        for (int q = 0; q < 4; ++q) {
            const int v = loc[q];
            c[tid * 4 + q]   = eb;
            cur[tid * 4 + q] = eb;
            eb += v;
        }
    }
    __syncthreads();

    if (tid < nsrc) row_start[srcbase + tid] = base + c[tid];

    for (int i = base + tid; i < end; i += 256) {
        const unsigned int rec = bucket_arr[i];   // L2-hot re-read
        const int ls = (int)(rec >> 17);
        const int pos = base + atomicAdd(&cur[ls], 1);
        pairs[pos] = rec & 0x1FFFFu;
    }
}

// ===========================================================================
// K5: gather (r10/r12/r13-proven CSR bf16 gather; ee computed in preload).
// ===========================================================================
__global__ void gather_bf16_kernel(const unsigned short* __restrict__ h_bf16,
                                   const float* __restrict__ s_left,
                                   const float* __restrict__ s_right,
                                   const int* __restrict__ row_start,
                                   const unsigned int* __restrict__ pairs,
                                   float* __restrict__ out) {
    const int gtid = blockIdx.x * blockDim.x + threadIdx.x;
    const int node = gtid >> 6;
    const int lane = threadIdx.x & 63;
    if (node >= N_NODES) return;

    const int beg = row_start[node];
    const int end = row_start[node + 1];
    const float sl = s_left[node];

    const int half = lane >> 5;
    const int hl   = lane & 31;
    const ushort4* __restrict__ hb4 = reinterpret_cast<const ushort4*>(h_bf16);

    float4 acc = make_float4(0.0f, 0.0f, 0.0f, 0.0f);
    float rs = 0.0f;

    for (int base = beg; base < end; base += 64) {
        const int m = min(64, end - base);   // wave-uniform
        int pd = 0; float pe = 0.0f;
        if (lane < m) {
            const unsigned int rec = __builtin_nontemporal_load(&pairs[base + lane]);
            pd = (int)rec;
            const float score = sl + s_right[pd];
            const float lr = score > 0.0f ? score : ALPHA * score;
            pe = __expf(-lr);
        }

        int j = 0;  // uniform across all lanes from here (r3 lesson)
        for (; j + 16 <= m; j += 16) {
            const int jj = j + half;
            int   d[8]; float e[8];
            #pragma unroll
            for (int k = 0; k < 8; ++k) {
                d[k] = __shfl(pd, jj + 2 * k);
                e[k] = __shfl(pe, jj + 2 * k);
            }
            ushort4 u[8];
            #pragma unroll
            for (int k = 0; k < 8; ++k) u[k] = hb4[(size_t)d[k] * 32 + hl];
            #pragma unroll
            for (int k = 0; k < 8; ++k) {
                rs    += e[k];
                acc.x += e[k] * bf2f(u[k].x);
                acc.y += e[k] * bf2f(u[k].y);
                acc.z += e[k] * bf2f(u[k].z);
                acc.w += e[k] * bf2f(u[k].w);
            }
        }
        for (; j + 8 <= m; j += 8) {
            const int jj = j + half;
            int   d[4]; float e[4];
            #pragma unroll
            for (int k = 0; k < 4; ++k) {
                d[k] = __shfl(pd, jj + 2 * k);
                e[k] = __shfl(pe, jj + 2 * k);
            }
            ushort4 u[4];
            #pragma unroll
            for (int k = 0; k < 4; ++k) u[k] = hb4[(size_t)d[k] * 32 + hl];
            #pragma unroll
            for (int k = 0; k < 4; ++k) {
                rs    += e[k];
                acc.x += e[k] * bf2f(u[k].x);
                acc.y += e[k] * bf2f(u[k].y);
                acc.z += e[k] * bf2f(u[k].z);
                acc.w += e[k] * bf2f(u[k].w);
            }
        }
        for (; j + 2 <= m; j += 2) {
            const int jj = j + half;
            const int   dd = __shfl(pd, jj);
            const float ee = __shfl(pe, jj);
            const ushort4 u = hb4[(size_t)dd * 32 + hl];
            rs += ee;
            acc.x += ee * bf2f(u.x);
            acc.y += ee * bf2f(u.y);
            acc.z += ee * bf2f(u.z);
            acc.w += ee * bf2f(u.w);
        }
        if (j < m) {
            const int   dd = __shfl(pd, j);
            float       ee = __shfl(pe, j);
            if (half == 1) ee = 0.0f;
            const ushort4 u = hb4[(size_t)dd * 32 + hl];
            rs += ee;
            acc.x += ee * bf2f(u.x);
            acc.y += ee * bf2f(u.y);
            acc.z += ee * bf2f(u.z);
            acc.w += ee * bf2f(u.w);
        }
    }

    acc.x += __shfl_xor(acc.x, 32);
    acc.y += __shfl_xor(acc.y, 32);
    acc.z += __shfl_xor(acc.z, 32);
    acc.w += __shfl_xor(acc.w, 32);
    rs    += __shfl_xor(rs, 32);

    if (half == 0) {
        const float inv = 1.0f / rs;
        float4 o;
        o.x = fmaxf(acc.x * inv, 0.0f);
        o.y = fmaxf(acc.y * inv, 0.0f);
        o.z = fmaxf(acc.z * inv, 0.0f);
        o.w = fmaxf(acc.w * inv, 0.0f);
        reinterpret_cast<float4*>(out)[(size_t)node * 32 + hl] = o;
    }
}

// ===========================================================================
// Last-resort fallback (atomic path, 1.2 MB).
// ===========================================================================
__global__ void score_kernel(const float* __restrict__ h,
                             const float* __restrict__ a,
                             float* __restrict__ s_left,
                             float* __restrict__ s_right) {
    const int gtid = blockIdx.x * blockDim.x + threadIdx.x;
    const int node = gtid >> 6;
    const int lane = threadIdx.x & 63;
    if (node >= N_NODES) return;
    const float2 hv = reinterpret_cast<const float2*>(h + (size_t)node * F_DIM)[lane];
    const float2 al = reinterpret_cast<const float2*>(a)[lane];
    const float2 ar = reinterpret_cast<const float2*>(a + F_DIM)[lane];
    float pl = hv.x * al.x + hv.y * al.y;
    float pr = hv.x * ar.x + hv.y * ar.y;
    #pragma unroll
    for (int off = 32; off > 0; off >>= 1) {
        pl += __shfl_down(pl, off);
        pr += __shfl_down(pr, off);
    }
    if (lane == 0) { s_left[node] = pl; s_right[node] = pr; }
}

__global__ void edge_atomic_kernel(const float* __restrict__ h,
                                   const int* __restrict__ src,
                                   const int* __restrict__ dst,
                                   const float* __restrict__ s_left,
                                   const float* __restrict__ s_right,
                                   float* __restrict__ out,
                                   float* __restrict__ rowsum) {
    const int gtid = blockIdx.x * blockDim.x + threadIdx.x;
    const int e = gtid >> 6;
    const int lane = threadIdx.x & 63;
    if (e >= E_EDGES) return;
    const int s = src[e];
    const int d = dst[e];
    const float score = s_left[s] + s_right[d];
    const float lr = score > 0.0f ? score : ALPHA * score;
    const float ee = __expf(-lr);
    if (lane == 0) atomicAdd(&rowsum[s], ee);
    const float2 hv = reinterpret_cast<const float2*>(h + (size_t)d * F_DIM)[lane];
    float* o = out + (size_t)s * F_DIM + (size_t)lane * 2;
    atomicAdd(o,     ee * hv.x);
    atomicAdd(o + 1, ee * hv.y);
}

__global__ void finalize_kernel(float* __restrict__ out,
                                const float* __restrict__ rowsum) {
    const int i = blockIdx.x * blockDim.x + threadIdx.x;
    const int total = N_NODES * (F_DIM / 4);
    if (i >= total) return;
    const int n = i / (F_DIM / 4);
    const float inv = 1.0f / rowsum[n];
    float4 v = reinterpret_cast<float4*>(out)[i];
    v.x = fmaxf(v.x * inv, 0.0f);
    v.y = fmaxf(v.y * inv, 0.0f);
    v.z = fmaxf(v.z * inv, 0.0f);
    v.w = fmaxf(v.w * inv, 0.0f);
    reinterpret_cast<float4*>(out)[i] = v;
}

extern "C" void kernel_launch(void* const* d_in, const int* in_sizes, int n_in,
                              void* d_out, int out_size, void* d_ws, size_t ws_size,
                              hipStream_t stream) {
    const float* h    = (const float*)d_in[0];   // [N, F]
    const float* a    = (const float*)d_in[1];   // [1, 2F]
    const int*   edge = (const int*)d_in[2];     // [2, E]
    const int*   src  = edge;
    const int*   dst  = edge + E_EDGES;
    float* out = (float*)d_out;

    const int wpb = 256 / 64;

    // ---- SORT TIER (~40.3 MB; ws >= 52.5 MB proven in r11) ----
    {
        char* wp = (char*)d_ws;
        unsigned int* pairs      = (unsigned int*)wp;  wp += (size_t)E_EDGES * sizeof(unsigned int); // 6.4MB
        unsigned int* bucket_arr = (unsigned int*)wp;  wp += (size_t)E_EDGES * sizeof(unsigned int); // 6.4MB
        float* s_left    = (float*)wp;   wp += (size_t)N_NODES * sizeof(float);
        float* s_right   = (float*)wp;   wp += (size_t)N_NODES * sizeof(float);
        int*   row_start = (int*)wp;     wp += (size_t)(N_NODES + 1) * sizeof(int);
        int*   cm        = (int*)wp;     wp += (size_t)NBUCK * NHB * sizeof(int);   // 625.6KB
        int*   btot      = (int*)wp;     wp += (size_t)NBUCK * sizeof(int);
        int*   bucketbase= (int*)wp;     wp += (size_t)(NBUCK + 1) * sizeof(int);
        unsigned short* h_bf16 = (unsigned short*)wp;
        wp += (size_t)N_NODES * F_DIM * sizeof(unsigned short);                      // 25.6MB
        const size_t needed = (size_t)(wp - (char*)d_ws);

        if (ws_size >= needed) {
            fused_score_hist_kernel<<<NHB + SCORE_BLOCKS, 256, 0, stream>>>(
                h, a, s_left, s_right, h_bf16, src, cm);
            row_scan_kernel<<<NBUCK, 512, 0, stream>>>(cm, btot);
            bucket_base_kernel<<<1, 512, 0, stream>>>(btot, bucketbase, row_start);
            bucket_scatter_kernel<<<NHB, 256, 0, stream>>>(src, dst, cm, bucketbase, bucket_arr);
            bucket_sort_kernel<<<NBUCK, 256, 0, stream>>>(
                bucket_arr, bucketbase, row_start, pairs);
            gather_bf16_kernel<<<(N_NODES + wpb - 1) / wpb, 256, 0, stream>>>(
                h_bf16, s_left, s_right, row_start, pairs, out);
            return;
        }
    }

    // ---- FALLBACK: atomic path (1.2 MB) ----
    float* fsl = (float*)d_ws;
    float* fsr = fsl + N_NODES;
    float* frs = fsr + N_NODES;
    (void)hipMemsetAsync(d_out, 0, (size_t)N_NODES * F_DIM * sizeof(float), stream);
    (void)hipMemsetAsync(frs, 0, (size_t)N_NODES * sizeof(float), stream);
    score_kernel<<<(N_NODES + wpb - 1) / wpb, 256, 0, stream>>>(h, a, fsl, fsr);
    edge_atomic_kernel<<<(E_EDGES + wpb - 1) / wpb, 256, 0, stream>>>(
        h, src, dst, fsl, fsr, out, frs);
    const int total = N_NODES * (F_DIM / 4);
    finalize_kernel<<<(total + 255) / 256, 256, 0, stream>>>(out, frs);
}

// Round 15
// 118.216 us; speedup vs baseline: 3.3881x; 1.1251x over previous
//
#include <hip/hip_runtime.h>

#define N_NODES 100000
#define E_EDGES 1600000
#define F_DIM 128
#define ALPHA 0.2f

#define BSH 8
#define NBUCK ((N_NODES + 255) >> 8)      // 391
#define NHB 400                            // hist/scatter blocks
#define EPB 4000                           // 400*4000 = 1.6M exactly
#define SCORE_BLOCKS (N_NODES / 16)        // 6250

__device__ __forceinline__ float bf2f(unsigned short s) {
    return __uint_as_float((unsigned)s << 16);
}
__device__ __forceinline__ unsigned short f2bf(float f) {
    unsigned u = __float_as_uint(f);
    return (unsigned short)((u + 0x7FFFu + ((u >> 16) & 1u)) >> 16);  // RNE
}

// ===========================================================================
// K1: fused score + pass-1 coarse histogram (src>>8 into cm[bucket][blk]).
// Hist: int4-vectorized edge stream, LDS-only counts, exclusive-cell stores.
// ===========================================================================
__global__ void fused_score_hist_kernel(const float* __restrict__ h,
                                        const float* __restrict__ a,
                                        float* __restrict__ s_left,
                                        float* __restrict__ s_right,
                                        unsigned short* __restrict__ h_bf16,
                                        const int* __restrict__ src,
                                        int* __restrict__ cm) {
    const int b = blockIdx.x;
    if (b < NHB) {
        __shared__ int lh[NBUCK];
        for (int k = threadIdx.x; k < NBUCK; k += 256) lh[k] = 0;
        __syncthreads();
        const int4* __restrict__ s4 = reinterpret_cast<const int4*>(src + b * EPB);
        for (int i = threadIdx.x; i < EPB / 4; i += 256) {
            const int4 v = s4[i];
            atomicAdd(&lh[v.x >> BSH], 1);
            atomicAdd(&lh[v.y >> BSH], 1);
            atomicAdd(&lh[v.z >> BSH], 1);
            atomicAdd(&lh[v.w >> BSH], 1);
        }
        __syncthreads();
        for (int k = threadIdx.x; k < NBUCK; k += 256)
            cm[k * NHB + b] = lh[k];
    } else {
        // ---- score role: 16 nodes per block, 16 lanes per node ----
        const int sb   = b - NHB;
        const int lane = threadIdx.x & 63;
        const int sub  = lane & 15;
        const int node = sb * 16 + (threadIdx.x >> 6) * 4 + (lane >> 4);

        const float4* __restrict__ h4 = reinterpret_cast<const float4*>(h);
        const float4* __restrict__ a4 = reinterpret_cast<const float4*>(a);

        const float4 ha = h4[(size_t)node * 32 + sub * 2];
        const float4 hb = h4[(size_t)node * 32 + sub * 2 + 1];
        const float4 al0 = a4[sub * 2],      al1 = a4[sub * 2 + 1];
        const float4 ar0 = a4[32 + sub * 2], ar1 = a4[32 + sub * 2 + 1];

        ushort4 o0, o1;
        o0.x = f2bf(ha.x); o0.y = f2bf(ha.y); o0.z = f2bf(ha.z); o0.w = f2bf(ha.w);
        o1.x = f2bf(hb.x); o1.y = f2bf(hb.y); o1.z = f2bf(hb.z); o1.w = f2bf(hb.w);
        ushort4* hbw = reinterpret_cast<ushort4*>(h_bf16);
        hbw[(size_t)node * 32 + sub * 2]     = o0;
        hbw[(size_t)node * 32 + sub * 2 + 1] = o1;

        float pl = ha.x * al0.x + ha.y * al0.y + ha.z * al0.z + ha.w * al0.w
                 + hb.x * al1.x + hb.y * al1.y + hb.z * al1.z + hb.w * al1.w;
        float pr = ha.x * ar0.x + ha.y * ar0.y + ha.z * ar0.z + ha.w * ar0.w
                 + hb.x * ar1.x + hb.y * ar1.y + hb.z * ar1.z + hb.w * ar1.w;

        #pragma unroll
        for (int off = 8; off > 0; off >>= 1) {
            pl += __shfl_down(pl, off);
            pr += __shfl_down(pr, off);
        }
        if (sub == 0) {
            s_left[node]  = pl;
            s_right[node] = pr;
        }
    }
}

// ===========================================================================
// K2a: per-bucket row scan (391 blocks x 512 thr), in-place, + bucket total.
// ===========================================================================
__global__ void row_scan_kernel(int* __restrict__ cm,
                                int* __restrict__ btot) {
    __shared__ int s[512];
    const int k = blockIdx.x;
    const int t = threadIdx.x;
    const int v = (t < NHB) ? cm[k * NHB + t] : 0;
    s[t] = v;
    __syncthreads();
    #pragma unroll
    for (int off = 1; off < 512; off <<= 1) {
        const int u = (t >= off) ? s[t - off] : 0;
        __syncthreads();
        s[t] += u;
        __syncthreads();
    }
    if (t < NHB) cm[k * NHB + t] = s[t] - v;     // exclusive within row
    if (t == 511) btot[k] = s[511];              // row total
}

// ===========================================================================
// K2b: exclusive scan of the 391 bucket totals -> bucketbase + sentinels.
// ===========================================================================
__global__ void bucket_base_kernel(const int* __restrict__ btot,
                                   int* __restrict__ bucketbase,
                                   int* __restrict__ row_start) {
    __shared__ int s[512];
    const int t = threadIdx.x;
    const int v = (t < NBUCK) ? btot[t] : 0;
    s[t] = v;
    __syncthreads();
    #pragma unroll
    for (int off = 1; off < 512; off <<= 1) {
        const int u = (t >= off) ? s[t - off] : 0;
        __syncthreads();
        s[t] += u;
        __syncthreads();
    }
    if (t < NBUCK) bucketbase[t] = s[t] - v;
    if (t == 0) {
        bucketbase[NBUCK] = E_EDGES;
        row_start[N_NODES] = E_EDGES;
    }
}

// ===========================================================================
// K3: re-stream edges (int4-vectorized); LDS cursors = bucketbase + cm ->
// (src&255)<<17|dst records into bucket-contiguous chunks (dense writes).
// ===========================================================================
__global__ void bucket_scatter_kernel(const int* __restrict__ src,
                                      const int* __restrict__ dst,
                                      const int* __restrict__ cm,
                                      const int* __restrict__ bucketbase,
                                      unsigned int* __restrict__ bucket_arr) {
    __shared__ int cur[NBUCK];
    const int b = blockIdx.x;
    for (int k = threadIdx.x; k < NBUCK; k += 256)
        cur[k] = bucketbase[k] + cm[k * NHB + b];
    __syncthreads();
    const int4* __restrict__ s4 = reinterpret_cast<const int4*>(src + b * EPB);
    const int4* __restrict__ d4 = reinterpret_cast<const int4*>(dst + b * EPB);
    for (int i = threadIdx.x; i < EPB / 4; i += 256) {
        const int4 sv = s4[i];
        const int4 dv = d4[i];
        int r;
        r = atomicAdd(&cur[sv.x >> BSH], 1);
        bucket_arr[r] = ((unsigned int)(sv.x & 255) << 17) | (unsigned int)dv.x;
        r = atomicAdd(&cur[sv.y >> BSH], 1);
        bucket_arr[r] = ((unsigned int)(sv.y & 255) << 17) | (unsigned int)dv.y;
        r = atomicAdd(&cur[sv.z >> BSH], 1);
        bucket_arr[r] = ((unsigned int)(sv.z & 255) << 17) | (unsigned int)dv.z;
        r = atomicAdd(&cur[sv.w >> BSH], 1);
        bucket_arr[r] = ((unsigned int)(sv.w & 255) << 17) | (unsigned int)dv.w;
    }
}

// ===========================================================================
// K4: one block per bucket (~4096 edges, 16KB, L2-hot). LDS count of 256
// srcs -> wave-0 scan -> exact row_start + grouped dst-only pairs.
// ===========================================================================
__global__ void bucket_sort_kernel(const unsigned int* __restrict__ bucket_arr,
                                   const int* __restrict__ bucketbase,
                                   int* __restrict__ row_start,
                                   unsigned int* __restrict__ pairs) {
    __shared__ int c[256];
    __shared__ int cur[256];
    const int b = blockIdx.x;
    const int tid = threadIdx.x;
    const int base = bucketbase[b];
    const int end  = bucketbase[b + 1];
    const int srcbase = b << BSH;
    const int nsrc = min(256, N_NODES - srcbase);

    c[tid] = 0;
    __syncthreads();
    for (int i = base + tid; i < end; i += 256)
        atomicAdd(&c[bucket_arr[i] >> 17], 1);
    __syncthreads();

    if (tid < 64) {                               // wave 0: exclusive scan of 256
        int loc[4]; int lsum = 0;
        #pragma unroll
        for (int q = 0; q < 4; ++q) { loc[q] = c[tid * 4 + q]; lsum += loc[q]; }
        int inc = lsum;
        #pragma unroll
        for (int off = 1; off < 64; off <<= 1) {
            const int v = __shfl_up(inc, off);
            if (tid >= off) inc += v;
        }
        int eb = inc - lsum;                      // exclusive over lanes
        #pragma unroll
        for (int q = 0; q < 4; ++q) {
            const int v = loc[q];
            c[tid * 4 + q]   = eb;
            cur[tid * 4 + q] = eb;
            eb += v;
        }
    }
    __syncthreads();

    if (tid < nsrc) row_start[srcbase + tid] = base + c[tid];

    for (int i = base + tid; i < end; i += 256) {
        const unsigned int rec = bucket_arr[i];   // L2-hot re-read
        const int ls = (int)(rec >> 17);
        const int pos = base + atomicAdd(&cur[ls], 1);
        pairs[pos] = rec & 0x1FFFFu;
    }
}

// ===========================================================================
// K5: gather (r14-proven CSR bf16 gather; ee computed in preload).
// ===========================================================================
__global__ void gather_bf16_kernel(const unsigned short* __restrict__ h_bf16,
                                   const float* __restrict__ s_left,
                                   const float* __restrict__ s_right,
                                   const int* __restrict__ row_start,
                                   const unsigned int* __restrict__ pairs,
                                   float* __restrict__ out) {
    const int gtid = blockIdx.x * blockDim.x + threadIdx.x;
    const int node = gtid >> 6;
    const int lane = threadIdx.x & 63;
    if (node >= N_NODES) return;

    const int beg = row_start[node];
    const int end = row_start[node + 1];
    const float sl = s_left[node];

    const int half = lane >> 5;
    const int hl   = lane & 31;
    const ushort4* __restrict__ hb4 = reinterpret_cast<const ushort4*>(h_bf16);

    float4 acc = make_float4(0.0f, 0.0f, 0.0f, 0.0f);
    float rs = 0.0f;

    for (int base = beg; base < end; base += 64) {
        const int m = min(64, end - base);   // wave-uniform
        int pd = 0; float pe = 0.0f;
        if (lane < m) {
            const unsigned int rec = __builtin_nontemporal_load(&pairs[base + lane]);
            pd = (int)rec;
            const float score = sl + s_right[pd];
            const float lr = score > 0.0f ? score : ALPHA * score;
            pe = __expf(-lr);
        }

        int j = 0;  // uniform across all lanes from here (r3 lesson)
        for (; j + 16 <= m; j += 16) {
            const int jj = j + half;
            int   d[8]; float e[8];
            #pragma unroll
            for (int k = 0; k < 8; ++k) {
                d[k] = __shfl(pd, jj + 2 * k);
                e[k] = __shfl(pe, jj + 2 * k);
            }
            ushort4 u[8];
            #pragma unroll
            for (int k = 0; k < 8; ++k) u[k] = hb4[(size_t)d[k] * 32 + hl];
            #pragma unroll
            for (int k = 0; k < 8; ++k) {
                rs    += e[k];
                acc.x += e[k] * bf2f(u[k].x);
                acc.y += e[k] * bf2f(u[k].y);
                acc.z += e[k] * bf2f(u[k].z);
                acc.w += e[k] * bf2f(u[k].w);
            }
        }
        for (; j + 8 <= m; j += 8) {
            const int jj = j + half;
            int   d[4]; float e[4];
            #pragma unroll
            for (int k = 0; k < 4; ++k) {
                d[k] = __shfl(pd, jj + 2 * k);
                e[k] = __shfl(pe, jj + 2 * k);
            }
            ushort4 u[4];
            #pragma unroll
            for (int k = 0; k < 4; ++k) u[k] = hb4[(size_t)d[k] * 32 + hl];
            #pragma unroll
            for (int k = 0; k < 4; ++k) {
                rs    += e[k];
                acc.x += e[k] * bf2f(u[k].x);
                acc.y += e[k] * bf2f(u[k].y);
                acc.z += e[k] * bf2f(u[k].z);
                acc.w += e[k] * bf2f(u[k].w);
            }
        }
        for (; j + 2 <= m; j += 2) {
            const int jj = j + half;
            const int   dd = __shfl(pd, jj);
            const float ee = __shfl(pe, jj);
            const ushort4 u = hb4[(size_t)dd * 32 + hl];
            rs += ee;
            acc.x += ee * bf2f(u.x);
            acc.y += ee * bf2f(u.y);
            acc.z += ee * bf2f(u.z);
            acc.w += ee * bf2f(u.w);
        }
        if (j < m) {
            const int   dd = __shfl(pd, j);
            float       ee = __shfl(pe, j);
            if (half == 1) ee = 0.0f;
            const ushort4 u = hb4[(size_t)dd * 32 + hl];
            rs += ee;
            acc.x += ee * bf2f(u.x);
            acc.y += ee * bf2f(u.y);
            acc.z += ee * bf2f(u.z);
            acc.w += ee * bf2f(u.w);
        }
    }

    acc.x += __shfl_xor(acc.x, 32);
    acc.y += __shfl_xor(acc.y, 32);
    acc.z += __shfl_xor(acc.z, 32);
    acc.w += __shfl_xor(acc.w, 32);
    rs    += __shfl_xor(rs, 32);

    if (half == 0) {
        const float inv = 1.0f / rs;
        float4 o;
        o.x = fmaxf(acc.x * inv, 0.0f);
        o.y = fmaxf(acc.y * inv, 0.0f);
        o.z = fmaxf(acc.z * inv, 0.0f);
        o.w = fmaxf(acc.w * inv, 0.0f);
        reinterpret_cast<float4*>(out)[(size_t)node * 32 + hl] = o;
    }
}

// ===========================================================================
// Last-resort fallback (atomic path, 1.2 MB).
// ===========================================================================
__global__ void score_kernel(const float* __restrict__ h,
                             const float* __restrict__ a,
                             float* __restrict__ s_left,
                             float* __restrict__ s_right) {
    const int gtid = blockIdx.x * blockDim.x + threadIdx.x;
    const int node = gtid >> 6;
    const int lane = threadIdx.x & 63;
    if (node >= N_NODES) return;
    const float2 hv = reinterpret_cast<const float2*>(h + (size_t)node * F_DIM)[lane];
    const float2 al = reinterpret_cast<const float2*>(a)[lane];
    const float2 ar = reinterpret_cast<const float2*>(a + F_DIM)[lane];
    float pl = hv.x * al.x + hv.y * al.y;
    float pr = hv.x * ar.x + hv.y * ar.y;
    #pragma unroll
    for (int off = 32; off > 0; off >>= 1) {
        pl += __shfl_down(pl, off);
        pr += __shfl_down(pr, off);
    }
    if (lane == 0) { s_left[node] = pl; s_right[node] = pr; }
}

__global__ void edge_atomic_kernel(const float* __restrict__ h,
                                   const int* __restrict__ src,
                                   const int* __restrict__ dst,
                                   const float* __restrict__ s_left,
                                   const float* __restrict__ s_right,
                                   float* __restrict__ out,
                                   float* __restrict__ rowsum) {
    const int gtid = blockIdx.x * blockDim.x + threadIdx.x;
    const int e = gtid >> 6;
    const int lane = threadIdx.x & 63;
    if (e >= E_EDGES) return;
    const int s = src[e];
    const int d = dst[e];
    const float score = s_left[s] + s_right[d];
    const float lr = score > 0.0f ? score : ALPHA * score;
    const float ee = __expf(-lr);
    if (lane == 0) atomicAdd(&rowsum[s], ee);
    const float2 hv = reinterpret_cast<const float2*>(h + (size_t)d * F_DIM)[lane];
    float* o = out + (size_t)s * F_DIM + (size_t)lane * 2;
    atomicAdd(o,     ee * hv.x);
    atomicAdd(o + 1, ee * hv.y);
}

__global__ void finalize_kernel(float* __restrict__ out,
                                const float* __restrict__ rowsum) {
    const int i = blockIdx.x * blockDim.x + threadIdx.x;
    const int total = N_NODES * (F_DIM / 4);
    if (i >= total) return;
    const int n = i / (F_DIM / 4);
    const float inv = 1.0f / rowsum[n];
    float4 v = reinterpret_cast<float4*>(out)[i];
    v.x = fmaxf(v.x * inv, 0.0f);
    v.y = fmaxf(v.y * inv, 0.0f);
    v.z = fmaxf(v.z * inv, 0.0f);
    v.w = fmaxf(v.w * inv, 0.0f);
    reinterpret_cast<float4*>(out)[i] = v;
}

extern "C" void kernel_launch(void* const* d_in, const int* in_sizes, int n_in,
                              void* d_out, int out_size, void* d_ws, size_t ws_size,
                              hipStream_t stream) {
    const float* h    = (const float*)d_in[0];   // [N, F]
    const float* a    = (const float*)d_in[1];   // [1, 2F]
    const int*   edge = (const int*)d_in[2];     // [2, E]
    const int*   src  = edge;
    const int*   dst  = edge + E_EDGES;
    float* out = (float*)d_out;

    const int wpb = 256 / 64;

    // ---- SORT TIER (~40.3 MB; ws >= 52.5 MB proven in r11) ----
    {
        char* wp = (char*)d_ws;
        unsigned int* pairs      = (unsigned int*)wp;  wp += (size_t)E_EDGES * sizeof(unsigned int); // 6.4MB
        unsigned int* bucket_arr = (unsigned int*)wp;  wp += (size_t)E_EDGES * sizeof(unsigned int); // 6.4MB
        float* s_left    = (float*)wp;   wp += (size_t)N_NODES * sizeof(float);
        float* s_right   = (float*)wp;   wp += (size_t)N_NODES * sizeof(float);
        int*   row_start = (int*)wp;     wp += (size_t)(N_NODES + 1) * sizeof(int);
        int*   cm        = (int*)wp;     wp += (size_t)NBUCK * NHB * sizeof(int);   // 625.6KB
        int*   btot      = (int*)wp;     wp += (size_t)NBUCK * sizeof(int);
        int*   bucketbase= (int*)wp;     wp += (size_t)(NBUCK + 1) * sizeof(int);
        unsigned short* h_bf16 = (unsigned short*)wp;
        wp += (size_t)N_NODES * F_DIM * sizeof(unsigned short);                      // 25.6MB
        const size_t needed = (size_t)(wp - (char*)d_ws);

        if (ws_size >= needed) {
            fused_score_hist_kernel<<<NHB + SCORE_BLOCKS, 256, 0, stream>>>(
                h, a, s_left, s_right, h_bf16, src, cm);
            row_scan_kernel<<<NBUCK, 512, 0, stream>>>(cm, btot);
            bucket_base_kernel<<<1, 512, 0, stream>>>(btot, bucketbase, row_start);
            bucket_scatter_kernel<<<NHB, 256, 0, stream>>>(src, dst, cm, bucketbase, bucket_arr);
            bucket_sort_kernel<<<NBUCK, 256, 0, stream>>>(
                bucket_arr, bucketbase, row_start, pairs);
            gather_bf16_kernel<<<(N_NODES + wpb - 1) / wpb, 256, 0, stream>>>(
                h_bf16, s_left, s_right, row_start, pairs, out);
            return;
        }
    }

    // ---- FALLBACK: atomic path (1.2 MB) ----
    float* fsl = (float*)d_ws;
    float* fsr = fsl + N_NODES;
    float* frs = fsr + N_NODES;
    (void)hipMemsetAsync(d_out, 0, (size_t)N_NODES * F_DIM * sizeof(float), stream);
    (void)hipMemsetAsync(frs, 0, (size_t)N_NODES * sizeof(float), stream);
    score_kernel<<<(N_NODES + wpb - 1) / wpb, 256, 0, stream>>>(h, a, fsl, fsr);
    edge_atomic_kernel<<<(E_EDGES + wpb - 1) / wpb, 256, 0, stream>>>(
        h, src, dst, fsl, fsr, out, frs);
    const int total = N_NODES * (F_DIM / 4);
    finalize_kernel<<<(total + 255) / 256, 256, 0, stream>>>(out, frs);
}